// Round 11
// baseline (1129.018 us; speedup 1.0000x reference)
//
#include <hip/hip_runtime.h>
#include <hip/hip_bf16.h>

#define NN 100000
#define NE 1600000
#define HID 512
#define LOW 128
#define NR  6
#define NBINS (NN * NR)
#define GBLK 6250            // gather blocks: NN*16/256

typedef short  bf16x8 __attribute__((ext_vector_type(8)));
typedef float  f32x4  __attribute__((ext_vector_type(4)));
typedef float  f32x8  __attribute__((ext_vector_type(8)));
typedef unsigned short u16x8 __attribute__((ext_vector_type(8)));

__device__ __forceinline__ unsigned short f2bf(float x) {
    __hip_bfloat16 h = __float2bfloat16(x);
    return __builtin_bit_cast(unsigned short, h);
}
__device__ __forceinline__ float bf2f(unsigned short u) {
    return __builtin_bit_cast(float, (unsigned int)u << 16);
}
__device__ __forceinline__ f32x8 cvt8(u16x8 u) {
    f32x8 r;
    #pragma unroll
    for (int i = 0; i < 8; ++i) r[i] = bf2f(u[i]);
    return r;
}

// ---------------------------------------------------------------------------
// Stage ITERS*32 rows of 128B (64 bf16 cols) into LDS, XOR-swizzled source
// (global_load_lds writes linearly: wave-uniform base + lane*16).
// ---------------------------------------------------------------------------
template<int ITERS>
__device__ __forceinline__ void stage_rows(const unsigned short* __restrict__ G,
                                           int r0, int k0, int Kstride, int Rmax,
                                           char* lds_base, int tid)
{
    #pragma unroll
    for (int is = 0; is < ITERS; ++is) {
        int L   = is * 4096 + tid * 16;
        int row = L >> 7;
        int c   = ((L >> 4) & 7) ^ (row & 7);
        int gr  = r0 + row;
        gr = (gr < Rmax) ? gr : (Rmax - 1);
        const char* src = (const char*)G + ((size_t)gr * Kstride + k0) * 2 + c * 16;
        __builtin_amdgcn_global_load_lds(
            (const __attribute__((address_space(1))) void*)src,
            (__attribute__((address_space(3))) void*)(lds_base + is * 4096 + (tid & 192) * 16),
            16, 0, 0);
    }
}

__device__ __forceinline__ bf16x8 lds_frag(const char* lds_base, int row, int clog)
{
    return *(const bf16x8*)(lds_base + row * 128 + ((clog ^ (row & 7)) << 4));
}

// ---------------------------------------------------------------------------
// bf16 MFMA GEMM: C(bf16) = relu(A @ Bt^T + bias). 128x128 tile, 4 waves.
// ---------------------------------------------------------------------------
__global__ __launch_bounds__(256, 2)
void gemm_bf16(const unsigned short* __restrict__ A,
               const unsigned short* __restrict__ Bt,
               const float* __restrict__ bias,
               unsigned short* __restrict__ C,
               int M, int N, int K)
{
    __shared__ __align__(16) char lA[16384];
    __shared__ __align__(16) char lB[16384];

    const int tid  = threadIdx.x;
    const int lane = tid & 63;
    const int wid  = tid >> 6;
    const int wm   = wid >> 1;
    const int wn   = wid & 1;
    const int m0   = blockIdx.y * 128;
    const int n0   = blockIdx.x * 128;

    f32x4 acc[4][4] = {};

    for (int k0 = 0; k0 < K; k0 += 64) {
        stage_rows<4>(A,  m0, k0, K, M, lA, tid);
        stage_rows<4>(Bt, n0, k0, K, N, lB, tid);
        __syncthreads();
        #pragma unroll
        for (int kk = 0; kk < 2; ++kk) {
            const int clog = kk * 4 + (lane >> 4);
            bf16x8 af[4], bfr[4];
            #pragma unroll
            for (int i = 0; i < 4; ++i)
                af[i] = lds_frag(lA, wm * 64 + i * 16 + (lane & 15), clog);
            #pragma unroll
            for (int j = 0; j < 4; ++j)
                bfr[j] = lds_frag(lB, wn * 64 + j * 16 + (lane & 15), clog);
            #pragma unroll
            for (int i = 0; i < 4; ++i)
                #pragma unroll
                for (int j = 0; j < 4; ++j)
                    acc[i][j] = __builtin_amdgcn_mfma_f32_16x16x32_bf16(
                        af[i], bfr[j], acc[i][j], 0, 0, 0);
        }
        __syncthreads();
    }

    const int col_l = lane & 15;
    const int rgrp  = lane >> 4;
    #pragma unroll
    for (int i = 0; i < 4; ++i) {
        #pragma unroll
        for (int j = 0; j < 4; ++j) {
            int col  = n0 + wn * 64 + j * 16 + col_l;
            float bv = bias[col];
            #pragma unroll
            for (int r = 0; r < 4; ++r) {
                int row = m0 + wm * 64 + i * 16 + rgrp * 4 + r;
                if (row < M)
                    C[(size_t)row * N + col] = f2bf(fmaxf(acc[i][j][r] + bv, 0.f));
            }
        }
    }
}

// ---------------------------------------------------------------------------
// MERGED kernel: gather blocks + skip-GEMM tile blocks, ~6:1 interleaved.
// Gather (latency/L3-bound) and MFMA tiles (matrix-pipe-bound) co-schedule
// on the same CUs -> skip GEMM hides in gather stall slots.
// Block mapping: q=(bid*CT)/T increments exactly CT times -> gemm tile q;
// all other blocks are gather block (bid - q).
// ---------------------------------------------------------------------------
__global__ __launch_bounds__(256)
void gather_skip(const unsigned short* __restrict__ h,
                 const int* __restrict__ rowstart,
                 const int* __restrict__ list,
                 unsigned short* __restrict__ S,
                 const unsigned short* __restrict__ hob,
                 const unsigned short* __restrict__ wst,
                 const float* __restrict__ bs,
                 unsigned short* __restrict__ skipb,
                 int tileOff, int CT, int T)
{
    __shared__ __align__(16) char lA[16384];
    __shared__ __align__(16) char lB[16384];

    const int bid = blockIdx.x;
    const int q   = (bid * CT) / T;
    const bool isGemm = (((bid + 1) * CT) / T) > q;

    if (isGemm) {
        // ---- skip-GEMM tile: skipb = relu(hob @ wst^T + bs), K=512 ----
        const int tile = tileOff + q;
        const int m0   = (tile >> 2) * 128;
        const int n0   = (tile & 3) * 128;
        const int tid  = threadIdx.x;
        const int lane = tid & 63;
        const int wid  = tid >> 6;
        const int wm   = wid >> 1;
        const int wn   = wid & 1;

        f32x4 acc[4][4] = {};

        for (int k0 = 0; k0 < HID; k0 += 64) {
            stage_rows<4>(hob, m0, k0, HID, NN,  lA, tid);
            stage_rows<4>(wst, n0, k0, HID, HID, lB, tid);
            __syncthreads();
            #pragma unroll
            for (int kk = 0; kk < 2; ++kk) {
                const int clog = kk * 4 + (lane >> 4);
                bf16x8 af[4], bfr[4];
                #pragma unroll
                for (int i = 0; i < 4; ++i)
                    af[i] = lds_frag(lA, wm * 64 + i * 16 + (lane & 15), clog);
                #pragma unroll
                for (int j = 0; j < 4; ++j)
                    bfr[j] = lds_frag(lB, wn * 64 + j * 16 + (lane & 15), clog);
                #pragma unroll
                for (int i = 0; i < 4; ++i)
                    #pragma unroll
                    for (int j = 0; j < 4; ++j)
                        acc[i][j] = __builtin_amdgcn_mfma_f32_16x16x32_bf16(
                            af[i], bfr[j], acc[i][j], 0, 0, 0);
            }
            __syncthreads();
        }

        const int col_l = lane & 15;
        const int rgrp  = lane >> 4;
        #pragma unroll
        for (int i = 0; i < 4; ++i) {
            #pragma unroll
            for (int j = 0; j < 4; ++j) {
                int col  = n0 + wn * 64 + j * 16 + col_l;
                float bv = bs[col];
                #pragma unroll
                for (int r = 0; r < 4; ++r) {
                    int row = m0 + wm * 64 + i * 16 + rgrp * 4 + r;
                    if (row < NN)
                        skipb[(size_t)row * HID + col] =
                            f2bf(fmaxf(acc[i][j][r] + bv, 0.f));
                }
            }
        }
        return;
    }

    // ---- gather path: quarter-wave per node, 6 concurrent relation chains ----
    const int g    = bid - q;
    const int v    = g * 16 + (threadIdx.x >> 4);
    const int lane = threadIdx.x & 15;
    const u16x8* hp = (const u16x8*)h;

    const int b0 = rowstart[v * NR + 0];
    const int b1 = rowstart[v * NR + 1];
    const int b2 = rowstart[v * NR + 2];
    const int b3 = rowstart[v * NR + 3];
    const int b4 = rowstart[v * NR + 4];
    const int b5 = rowstart[v * NR + 5];
    const int b6 = rowstart[v * NR + 6];
    const int n0 = b1 - b0, n1 = b2 - b1, n2 = b3 - b2;
    const int n3 = b4 - b3, n4 = b5 - b4, n5 = b6 - b5;
    const int kmax = max(max(max(n0, n1), max(n2, n3)), max(n4, n5));

    f32x8 a0 = {}, a1 = {}, a2 = {}, a3 = {}, a4 = {}, a5 = {};

    for (int k = 0; k < kmax; ++k) {
        int i0 = (k < n0) ? (b0 + k) : 0;
        int i1 = (k < n1) ? (b1 + k) : 0;
        int i2 = (k < n2) ? (b2 + k) : 0;
        int i3 = (k < n3) ? (b3 + k) : 0;
        int i4 = (k < n4) ? (b4 + k) : 0;
        int i5 = (k < n5) ? (b5 + k) : 0;
        int s0 = list[i0], s1 = list[i1], s2 = list[i2];
        int s3 = list[i3], s4 = list[i4], s5 = list[i5];
        u16x8 u0 = hp[(size_t)s0 * 16 + lane];
        u16x8 u1 = hp[(size_t)s1 * 16 + lane];
        u16x8 u2 = hp[(size_t)s2 * 16 + lane];
        u16x8 u3 = hp[(size_t)s3 * 16 + lane];
        u16x8 u4 = hp[(size_t)s4 * 16 + lane];
        u16x8 u5 = hp[(size_t)s5 * 16 + lane];
        if (k < n0) a0 += cvt8(u0);
        if (k < n1) a1 += cvt8(u1);
        if (k < n2) a2 += cvt8(u2);
        if (k < n3) a3 += cvt8(u3);
        if (k < n4) a4 += cvt8(u4);
        if (k < n5) a5 += cvt8(u5);
    }

    u16x8* o = (u16x8*)(S + (size_t)v * (NR * LOW));
    u16x8 w;
    #pragma unroll
    for (int i = 0; i < 8; ++i) w[i] = f2bf(a0[i]);
    __builtin_nontemporal_store(w, &o[0 * 16 + lane]);
    #pragma unroll
    for (int i = 0; i < 8; ++i) w[i] = f2bf(a1[i]);
    __builtin_nontemporal_store(w, &o[1 * 16 + lane]);
    #pragma unroll
    for (int i = 0; i < 8; ++i) w[i] = f2bf(a2[i]);
    __builtin_nontemporal_store(w, &o[2 * 16 + lane]);
    #pragma unroll
    for (int i = 0; i < 8; ++i) w[i] = f2bf(a3[i]);
    __builtin_nontemporal_store(w, &o[3 * 16 + lane]);
    #pragma unroll
    for (int i = 0; i < 8; ++i) w[i] = f2bf(a4[i]);
    __builtin_nontemporal_store(w, &o[4 * 16 + lane]);
    #pragma unroll
    for (int i = 0; i < 8; ++i) w[i] = f2bf(a5[i]);
    __builtin_nontemporal_store(w, &o[5 * 16 + lane]);
}

// ---------------------------------------------------------------------------
// Upper + skip add: out(f32) = relu(h @ Wut^T + bu) + skipb.  K=128 only.
// 1-D grid (3128 = 8*391), XCD swizzle, n-fastest.
// ---------------------------------------------------------------------------
__global__ __launch_bounds__(256, 2)
void gemm_out_upper(const unsigned short* __restrict__ h,
                    const unsigned short* __restrict__ Wut,
                    const float* __restrict__ bu,
                    const unsigned short* __restrict__ skipb,
                    float* __restrict__ out, int M)
{
    __shared__ __align__(16) char lA[16384];
    __shared__ __align__(16) char lB[16384];

    const int tid  = threadIdx.x;
    const int lane = tid & 63;
    const int wid  = tid >> 6;
    const int wm   = wid >> 1;
    const int wn   = wid & 1;

    const int nwg  = gridDim.x;            // 3128 = 8 * 391
    const int cpx  = nwg >> 3;
    const int idx  = (blockIdx.x & 7) * cpx + (blockIdx.x >> 3);
    const int m0   = (idx >> 2) * 128;
    const int n0   = (idx & 3) * 128;

    f32x4 acc[4][4] = {};

    for (int k0 = 0; k0 < LOW; k0 += 64) {
        stage_rows<4>(h,   m0, k0, LOW, M,   lA, tid);
        stage_rows<4>(Wut, n0, k0, LOW, HID, lB, tid);
        __syncthreads();
        #pragma unroll
        for (int kk = 0; kk < 2; ++kk) {
            const int clog = kk * 4 + (lane >> 4);
            bf16x8 af[4], bfr[4];
            #pragma unroll
            for (int i = 0; i < 4; ++i)
                af[i] = lds_frag(lA, wm * 64 + i * 16 + (lane & 15), clog);
            #pragma unroll
            for (int j = 0; j < 4; ++j)
                bfr[j] = lds_frag(lB, wn * 64 + j * 16 + (lane & 15), clog);
            #pragma unroll
            for (int i = 0; i < 4; ++i)
                #pragma unroll
                for (int j = 0; j < 4; ++j)
                    acc[i][j] = __builtin_amdgcn_mfma_f32_16x16x32_bf16(
                        af[i], bfr[j], acc[i][j], 0, 0, 0);
        }
        __syncthreads();
    }

    const int col_l = lane & 15;
    const int rgrp  = lane >> 4;
    #pragma unroll
    for (int i = 0; i < 4; ++i) {
        #pragma unroll
        for (int j = 0; j < 4; ++j) {
            int col  = n0 + wn * 64 + j * 16 + col_l;
            float bv = bu[col];
            #pragma unroll
            for (int r = 0; r < 4; ++r) {
                int row = m0 + wm * 64 + i * 16 + rgrp * 4 + r;
                if (row < M) {
                    float sk = bf2f(skipb[(size_t)row * HID + col]);
                    out[(size_t)row * HID + col] =
                        fmaxf(acc[i][j][r] + bv, 0.f) + sk;
                }
            }
        }
    }
}

// ---------------------------------------------------------------------------
// Conversions
// ---------------------------------------------------------------------------
__global__ __launch_bounds__(256)
void conv_f32_bf16(const float4* __restrict__ in, ushort4* __restrict__ out, int n4)
{
    for (int i = blockIdx.x * 256 + threadIdx.x; i < n4; i += gridDim.x * 256) {
        float4 v = in[i];
        ushort4 o;
        o.x = f2bf(v.x); o.y = f2bf(v.y); o.z = f2bf(v.z); o.w = f2bf(v.w);
        out[i] = o;
    }
}

__global__ __launch_bounds__(256)
void transpose_bf16(const float* __restrict__ W, unsigned short* __restrict__ Wt,
                    int R, int C)
{
    int idx = blockIdx.x * 256 + threadIdx.x;
    if (idx < R * C) {
        int r = idx / C, c = idx - r * C;
        Wt[(size_t)c * R + r] = f2bf(W[idx]);
    }
}

// ---------------------------------------------------------------------------
// CSR build keyed by bin = dst*NR + rel. Parallel 3-kernel exclusive scan.
// ---------------------------------------------------------------------------
#define SCAN_VT 8
#define SCAN_BS 256
#define SCAN_CHUNK (SCAN_VT * SCAN_BS)
#define SCAN_NB ((NBINS + SCAN_CHUNK - 1) / SCAN_CHUNK)

__global__ __launch_bounds__(256)
void k_hist(const int* __restrict__ dst, const int* __restrict__ typ,
            int* __restrict__ deg, int E)
{
    int e = blockIdx.x * 256 + threadIdx.x;
    if (e < E) atomicAdd(&deg[dst[e] * NR + typ[e]], 1);
}

__global__ __launch_bounds__(SCAN_BS)
void k_scan_part(const int* __restrict__ deg, int* __restrict__ blocksum, int n)
{
    __shared__ int ps[SCAN_BS];
    const int t = threadIdx.x;
    const int lo = blockIdx.x * SCAN_CHUNK + t * SCAN_VT;
    int s = 0;
    #pragma unroll
    for (int k = 0; k < SCAN_VT; ++k) {
        int i = lo + k;
        if (i < n) s += deg[i];
    }
    ps[t] = s;
    __syncthreads();
    for (int off = SCAN_BS / 2; off > 0; off >>= 1) {
        if (t < off) ps[t] += ps[t + off];
        __syncthreads();
    }
    if (t == 0) blocksum[blockIdx.x] = ps[0];
}

__global__ __launch_bounds__(64)
void k_scan_mid(const int* __restrict__ blocksum, int* __restrict__ blockoff,
                int* __restrict__ rowstart, int nb, int n)
{
    if (threadIdx.x == 0) {
        int run = 0;
        for (int i = 0; i < nb; ++i) { blockoff[i] = run; run += blocksum[i]; }
        rowstart[n] = run;
    }
}

__global__ __launch_bounds__(SCAN_BS)
void k_scan_final(const int* __restrict__ deg, const int* __restrict__ blockoff,
                  int* __restrict__ rowstart, int* __restrict__ cursor, int n)
{
    __shared__ int ps[SCAN_BS];
    const int t = threadIdx.x;
    const int lo = blockIdx.x * SCAN_CHUNK + t * SCAN_VT;
    int local[SCAN_VT];
    int s = 0;
    #pragma unroll
    for (int k = 0; k < SCAN_VT; ++k) {
        int i = lo + k;
        int v = (i < n) ? deg[i] : 0;
        local[k] = v;
        s += v;
    }
    ps[t] = s;
    __syncthreads();
    for (int off = 1; off < SCAN_BS; off <<= 1) {
        int v = (t >= off) ? ps[t - off] : 0;
        __syncthreads();
        ps[t] += v;
        __syncthreads();
    }
    int run = blockoff[blockIdx.x] + ((t > 0) ? ps[t - 1] : 0);
    #pragma unroll
    for (int k = 0; k < SCAN_VT; ++k) {
        int i = lo + k;
        if (i < n) {
            rowstart[i] = run;
            cursor[i]   = run;
            run += local[k];
        }
    }
}

__global__ __launch_bounds__(256)
void k_fill(const int* __restrict__ src, const int* __restrict__ dst,
            const int* __restrict__ typ, int* __restrict__ cursor,
            int* __restrict__ list, int E)
{
    int e = blockIdx.x * 256 + threadIdx.x;
    if (e < E) {
        int pos = atomicAdd(&cursor[dst[e] * NR + typ[e]], 1);
        list[pos] = src[e];
    }
}

extern "C" void kernel_launch(void* const* d_in, const int* in_sizes, int n_in,
                              void* d_out, int out_size, void* d_ws, size_t ws_size,
                              hipStream_t stream)
{
    (void)in_sizes; (void)n_in; (void)out_size; (void)ws_size;

    const float* h_origin = (const float*)d_in[0];
    const int*   esrc     = (const int*)d_in[1];
    const int*   edst     = (const int*)d_in[2];
    const int*   etyp     = (const int*)d_in[3];
    const float* W_lower  = (const float*)d_in[4];
    const float* b_lower  = (const float*)d_in[5];
    const float* Wl[3]    = {(const float*)d_in[6], (const float*)d_in[8], (const float*)d_in[10]};
    const float* bl[3]    = {(const float*)d_in[7], (const float*)d_in[9], (const float*)d_in[11]};
    const float* W_upper  = (const float*)d_in[12];
    const float* b_upper  = (const float*)d_in[13];
    const float* W_skip   = (const float*)d_in[14];
    const float* b_skip   = (const float*)d_in[15];
    float*       out      = (float*)d_out;

    // Workspace layout (~399 MB; proven ws >= ~417 MB in round 1/2)
    unsigned short* hob   = (unsigned short*)d_ws;          // [NN,512] bf16
    unsigned short* h     = hob + (size_t)NN * HID;         // [NN,128]
    unsigned short* S     = h + (size_t)NN * LOW;           // [NN,768]
    unsigned short* skipb = S + (size_t)NN * NR * LOW;      // [NN,512] bf16
    unsigned short* wlt   = skipb + (size_t)NN * HID;       // [128,512]^T
    unsigned short* w1t   = wlt + (size_t)LOW * HID;        // [128,768]^T x3
    unsigned short* w2t   = w1t + (size_t)LOW * NR * LOW;
    unsigned short* w3t   = w2t + (size_t)LOW * NR * LOW;
    unsigned short* wut   = w3t + (size_t)LOW * NR * LOW;   // [512,128]^T
    unsigned short* wst   = wut + (size_t)HID * LOW;        // [512,512]^T
    int* deg      = (int*)(wst + (size_t)HID * HID);        // [NBINS]
    int* rowstart = deg + NBINS;                            // [NBINS+1]
    int* cursor   = rowstart + NBINS + 1;                   // [NBINS]
    int* list     = cursor + NBINS;                         // [NE]
    int* blocksum = list + NE;                              // [SCAN_NB]
    int* blockoff = blocksum + SCAN_NB;                     // [SCAN_NB]
    unsigned short* wtL[3] = {w1t, w2t, w3t};

    const unsigned eBlocks = (unsigned)((NE + 255) / 256);
    const unsigned mBlocks = (unsigned)((NN + 127) / 128);   // 782

    // ---- conversions ----
    conv_f32_bf16<<<dim3(2048), dim3(256), 0, stream>>>(
        (const float4*)h_origin, (ushort4*)hob, NN * HID / 4);
    transpose_bf16<<<dim3((HID * LOW + 255) / 256), dim3(256), 0, stream>>>(
        W_lower, wlt, HID, LOW);
    for (int L = 0; L < 3; ++L)
        transpose_bf16<<<dim3((NR * LOW * LOW + 255) / 256), dim3(256), 0, stream>>>(
            Wl[L], wtL[L], NR * LOW, LOW);
    transpose_bf16<<<dim3((LOW * HID + 255) / 256), dim3(256), 0, stream>>>(
        W_upper, wut, LOW, HID);
    transpose_bf16<<<dim3((HID * HID + 255) / 256), dim3(256), 0, stream>>>(
        W_skip, wst, HID, HID);

    // ---- CSR build over (dst, rel) bins ----
    hipMemsetAsync(deg, 0, NBINS * sizeof(int), stream);
    k_hist<<<dim3(eBlocks), dim3(256), 0, stream>>>(edst, etyp, deg, NE);
    k_scan_part<<<dim3(SCAN_NB), dim3(SCAN_BS), 0, stream>>>(deg, blocksum, NBINS);
    k_scan_mid<<<dim3(1), dim3(64), 0, stream>>>(blocksum, blockoff, rowstart, SCAN_NB, NBINS);
    k_scan_final<<<dim3(SCAN_NB), dim3(SCAN_BS), 0, stream>>>(deg, blockoff, rowstart, cursor, NBINS);
    k_fill<<<dim3(eBlocks), dim3(256), 0, stream>>>(esrc, edst, etyp, cursor, list, NE);

    // ---- lower: h = relu(hob @ wlt^T + b_lower) ----
    gemm_bf16<<<dim3(1, mBlocks), dim3(256), 0, stream>>>(
        hob, wlt, b_lower, h, NN, LOW, HID);

    // ---- 3 R-GCN layers; skip GEMM (3128 tiles) co-scheduled in chunks ----
    const int CTs[3]  = {1043, 1043, 1042};
    const int offs[3] = {0, 1043, 2086};
    for (int L = 0; L < 3; ++L) {
        int T = GBLK + CTs[L];
        gather_skip<<<dim3((unsigned)T), dim3(256), 0, stream>>>(
            h, rowstart, list, S, hob, wst, b_skip, skipb, offs[L], CTs[L], T);
        gemm_bf16<<<dim3(1, mBlocks), dim3(256), 0, stream>>>(
            S, wtL[L], bl[L], h, NN, LOW, NR * LOW);
    }

    // ---- out = relu(h @ wut^T + bu) + skipb ----
    gemm_out_upper<<<dim3((HID / 128) * mBlocks), dim3(256), 0, stream>>>(
        h, wut, b_upper, skipb, out, NN);
}

// Round 12
// 846.992 us; speedup vs baseline: 1.3330x; 1.3330x over previous
//
#include <hip/hip_runtime.h>
#include <hip/hip_bf16.h>

#define NN 100000
#define NE 1600000
#define HID 512
#define LOW 128
#define NR  6
#define NBINS (NN * NR)

typedef short  bf16x8 __attribute__((ext_vector_type(8)));
typedef float  f32x4  __attribute__((ext_vector_type(4)));
typedef float  f32x8  __attribute__((ext_vector_type(8)));
typedef unsigned short u16x8 __attribute__((ext_vector_type(8)));

__device__ __forceinline__ unsigned short f2bf(float x) {
    __hip_bfloat16 h = __float2bfloat16(x);
    return __builtin_bit_cast(unsigned short, h);
}
__device__ __forceinline__ float bf2f(unsigned short u) {
    return __builtin_bit_cast(float, (unsigned int)u << 16);
}
__device__ __forceinline__ f32x8 cvt8(u16x8 u) {
    f32x8 r;
    #pragma unroll
    for (int i = 0; i < 8; ++i) r[i] = bf2f(u[i]);
    return r;
}

// ---------------------------------------------------------------------------
// Stage 128 rows x 128B (64 bf16 cols) into LDS, XOR-swizzled source
// (global_load_lds writes linearly: wave-uniform base + lane*16).
// ---------------------------------------------------------------------------
__device__ __forceinline__ void stage_rows(const unsigned short* __restrict__ G,
                                           int r0, int k0, int Kstride, int Rmax,
                                           char* lds_base, int tid)
{
    #pragma unroll
    for (int is = 0; is < 4; ++is) {
        int L   = is * 4096 + tid * 16;
        int row = L >> 7;
        int c   = ((L >> 4) & 7) ^ (row & 7);
        int gr  = r0 + row;
        gr = (gr < Rmax) ? gr : (Rmax - 1);
        const char* src = (const char*)G + ((size_t)gr * Kstride + k0) * 2 + c * 16;
        __builtin_amdgcn_global_load_lds(
            (const __attribute__((address_space(1))) void*)src,
            (__attribute__((address_space(3))) void*)(lds_base + is * 4096 + (tid & 192) * 16),
            16, 0, 0);
    }
}

__device__ __forceinline__ bf16x8 lds_frag(const char* lds_base, int row, int clog)
{
    return *(const bf16x8*)(lds_base + row * 128 + ((clog ^ (row & 7)) << 4));
}

// ---------------------------------------------------------------------------
// bf16 MFMA GEMM, 2-PHASE double-buffered: stage(next) issued BEFORE MFMA(cur);
// one barrier per K-step (its implicit vmcnt(0) drains the prefetch AFTER the
// MFMA has covered the latency). 128x128 tile, 4 waves.
// ---------------------------------------------------------------------------
__global__ __launch_bounds__(256, 2)
void gemm_bf16(const unsigned short* __restrict__ A,
               const unsigned short* __restrict__ Bt,
               const float* __restrict__ bias,
               unsigned short* __restrict__ C,
               int M, int N, int K)
{
    __shared__ __align__(16) char lA[2][16384];
    __shared__ __align__(16) char lB[2][16384];

    const int tid  = threadIdx.x;
    const int lane = tid & 63;
    const int wid  = tid >> 6;
    const int wm   = wid >> 1;
    const int wn   = wid & 1;
    const int m0   = blockIdx.y * 128;
    const int n0   = blockIdx.x * 128;

    f32x4 acc[4][4] = {};

    stage_rows(A,  m0, 0, K, M, lA[0], tid);
    stage_rows(Bt, n0, 0, K, N, lB[0], tid);
    __syncthreads();

    const int nsteps = K >> 6;
    int cur = 0;
    for (int s = 0; s < nsteps; ++s) {
        int nxt = cur ^ 1;
        if (s + 1 < nsteps) {
            stage_rows(A,  m0, (s + 1) << 6, K, M, lA[nxt], tid);
            stage_rows(Bt, n0, (s + 1) << 6, K, N, lB[nxt], tid);
        }
        #pragma unroll
        for (int kk = 0; kk < 2; ++kk) {
            const int clog = kk * 4 + (lane >> 4);
            bf16x8 af[4], bfr[4];
            #pragma unroll
            for (int i = 0; i < 4; ++i)
                af[i] = lds_frag(lA[cur], wm * 64 + i * 16 + (lane & 15), clog);
            #pragma unroll
            for (int j = 0; j < 4; ++j)
                bfr[j] = lds_frag(lB[cur], wn * 64 + j * 16 + (lane & 15), clog);
            #pragma unroll
            for (int i = 0; i < 4; ++i)
                #pragma unroll
                for (int j = 0; j < 4; ++j)
                    acc[i][j] = __builtin_amdgcn_mfma_f32_16x16x32_bf16(
                        af[i], bfr[j], acc[i][j], 0, 0, 0);
        }
        __syncthreads();
        cur = nxt;
    }

    const int col_l = lane & 15;
    const int rgrp  = lane >> 4;
    #pragma unroll
    for (int i = 0; i < 4; ++i) {
        #pragma unroll
        for (int j = 0; j < 4; ++j) {
            int col  = n0 + wn * 64 + j * 16 + col_l;
            float bv = bias[col];
            #pragma unroll
            for (int r = 0; r < 4; ++r) {
                int row = m0 + wm * 64 + i * 16 + rgrp * 4 + r;
                if (row < M)
                    C[(size_t)row * N + col] = f2bf(fmaxf(acc[i][j][r] + bv, 0.f));
            }
        }
    }
}

// ---------------------------------------------------------------------------
// Fused output, 2-PHASE double-buffered (prefetch crosses the upper->skip
// boundary): out(f32) = relu(h @ Wut^T + bu) + relu(hob @ Wst^T + bs).
// 1-D grid (3128 = 8*391), XCD swizzle, plain stores.
// ---------------------------------------------------------------------------
__global__ __launch_bounds__(256, 2)
void gemm_out_fused(const unsigned short* __restrict__ h,
                    const unsigned short* __restrict__ Wut,
                    const float* __restrict__ bu,
                    const unsigned short* __restrict__ hob,
                    const unsigned short* __restrict__ Wst,
                    const float* __restrict__ bs,
                    float* __restrict__ out, int M)
{
    __shared__ __align__(16) char lA[2][16384];
    __shared__ __align__(16) char lB[2][16384];

    const int tid  = threadIdx.x;
    const int lane = tid & 63;
    const int wid  = tid >> 6;
    const int wm   = wid >> 1;
    const int wn   = wid & 1;

    const int nwg  = gridDim.x;            // 3128 = 8 * 391
    const int cpx  = nwg >> 3;
    const int idx  = (blockIdx.x & 7) * cpx + (blockIdx.x >> 3);
    const int m0   = (idx >> 2) * 128;
    const int n0   = (idx & 3) * 128;

    f32x4 acc1[4][4] = {};
    f32x4 acc2[4][4] = {};

    stage_rows(h,   m0, 0, LOW, M,   lA[0], tid);
    stage_rows(Wut, n0, 0, LOW, HID, lB[0], tid);
    __syncthreads();

    int cur = 0;
    // phase 1: upper (K=128, 2 steps); prefetch step s+1, crossing into phase 2
    for (int s = 0; s < 2; ++s) {
        int nxt = cur ^ 1;
        if (s == 0) {
            stage_rows(h,   m0, 64, LOW, M,   lA[nxt], tid);
            stage_rows(Wut, n0, 64, LOW, HID, lB[nxt], tid);
        } else {
            stage_rows(hob, m0, 0, HID, M,   lA[nxt], tid);
            stage_rows(Wst, n0, 0, HID, HID, lB[nxt], tid);
        }
        #pragma unroll
        for (int kk = 0; kk < 2; ++kk) {
            const int clog = kk * 4 + (lane >> 4);
            bf16x8 af[4], bfr[4];
            #pragma unroll
            for (int i = 0; i < 4; ++i)
                af[i] = lds_frag(lA[cur], wm * 64 + i * 16 + (lane & 15), clog);
            #pragma unroll
            for (int j = 0; j < 4; ++j)
                bfr[j] = lds_frag(lB[cur], wn * 64 + j * 16 + (lane & 15), clog);
            #pragma unroll
            for (int i = 0; i < 4; ++i)
                #pragma unroll
                for (int j = 0; j < 4; ++j)
                    acc1[i][j] = __builtin_amdgcn_mfma_f32_16x16x32_bf16(
                        af[i], bfr[j], acc1[i][j], 0, 0, 0);
        }
        __syncthreads();
        cur = nxt;
    }
    // phase 2: skip (K=512, 8 steps)
    for (int s = 0; s < 8; ++s) {
        int nxt = cur ^ 1;
        if (s + 1 < 8) {
            stage_rows(hob, m0, (s + 1) << 6, HID, M,   lA[nxt], tid);
            stage_rows(Wst, n0, (s + 1) << 6, HID, HID, lB[nxt], tid);
        }
        #pragma unroll
        for (int kk = 0; kk < 2; ++kk) {
            const int clog = kk * 4 + (lane >> 4);
            bf16x8 af[4], bfr[4];
            #pragma unroll
            for (int i = 0; i < 4; ++i)
                af[i] = lds_frag(lA[cur], wm * 64 + i * 16 + (lane & 15), clog);
            #pragma unroll
            for (int j = 0; j < 4; ++j)
                bfr[j] = lds_frag(lB[cur], wn * 64 + j * 16 + (lane & 15), clog);
            #pragma unroll
            for (int i = 0; i < 4; ++i)
                #pragma unroll
                for (int j = 0; j < 4; ++j)
                    acc2[i][j] = __builtin_amdgcn_mfma_f32_16x16x32_bf16(
                        af[i], bfr[j], acc2[i][j], 0, 0, 0);
        }
        __syncthreads();
        cur = nxt;
    }

    const int col_l = lane & 15;
    const int rgrp  = lane >> 4;
    #pragma unroll
    for (int i = 0; i < 4; ++i) {
        #pragma unroll
        for (int j = 0; j < 4; ++j) {
            int col   = n0 + wn * 64 + j * 16 + col_l;
            float bv1 = bu[col], bv2 = bs[col];
            #pragma unroll
            for (int r = 0; r < 4; ++r) {
                int row = m0 + wm * 64 + i * 16 + rgrp * 4 + r;
                if (row < M)
                    out[(size_t)row * HID + col] =
                        fmaxf(acc1[i][j][r] + bv1, 0.f) + fmaxf(acc2[i][j][r] + bv2, 0.f);
            }
        }
    }
}

// ---------------------------------------------------------------------------
// Conversions
// ---------------------------------------------------------------------------
__global__ __launch_bounds__(256)
void conv_f32_bf16(const float4* __restrict__ in, ushort4* __restrict__ out, int n4)
{
    for (int i = blockIdx.x * 256 + threadIdx.x; i < n4; i += gridDim.x * 256) {
        float4 v = in[i];
        ushort4 o;
        o.x = f2bf(v.x); o.y = f2bf(v.y); o.z = f2bf(v.z); o.w = f2bf(v.w);
        out[i] = o;
    }
}

__global__ __launch_bounds__(256)
void transpose_bf16(const float* __restrict__ W, unsigned short* __restrict__ Wt,
                    int R, int C)
{
    int idx = blockIdx.x * 256 + threadIdx.x;
    if (idx < R * C) {
        int r = idx / C, c = idx - r * C;
        Wt[(size_t)c * R + r] = f2bf(W[idx]);
    }
}

// ---------------------------------------------------------------------------
// CSR build keyed by bin = dst*NR + rel. Parallel 3-kernel exclusive scan.
// ---------------------------------------------------------------------------
#define SCAN_VT 8
#define SCAN_BS 256
#define SCAN_CHUNK (SCAN_VT * SCAN_BS)
#define SCAN_NB ((NBINS + SCAN_CHUNK - 1) / SCAN_CHUNK)

__global__ __launch_bounds__(256)
void k_hist(const int* __restrict__ dst, const int* __restrict__ typ,
            int* __restrict__ deg, int E)
{
    int e = blockIdx.x * 256 + threadIdx.x;
    if (e < E) atomicAdd(&deg[dst[e] * NR + typ[e]], 1);
}

__global__ __launch_bounds__(SCAN_BS)
void k_scan_part(const int* __restrict__ deg, int* __restrict__ blocksum, int n)
{
    __shared__ int ps[SCAN_BS];
    const int t = threadIdx.x;
    const int lo = blockIdx.x * SCAN_CHUNK + t * SCAN_VT;
    int s = 0;
    #pragma unroll
    for (int k = 0; k < SCAN_VT; ++k) {
        int i = lo + k;
        if (i < n) s += deg[i];
    }
    ps[t] = s;
    __syncthreads();
    for (int off = SCAN_BS / 2; off > 0; off >>= 1) {
        if (t < off) ps[t] += ps[t + off];
        __syncthreads();
    }
    if (t == 0) blocksum[blockIdx.x] = ps[0];
}

__global__ __launch_bounds__(64)
void k_scan_mid(const int* __restrict__ blocksum, int* __restrict__ blockoff,
                int* __restrict__ rowstart, int nb, int n)
{
    if (threadIdx.x == 0) {
        int run = 0;
        for (int i = 0; i < nb; ++i) { blockoff[i] = run; run += blocksum[i]; }
        rowstart[n] = run;
    }
}

__global__ __launch_bounds__(SCAN_BS)
void k_scan_final(const int* __restrict__ deg, const int* __restrict__ blockoff,
                  int* __restrict__ rowstart, int* __restrict__ cursor, int n)
{
    __shared__ int ps[SCAN_BS];
    const int t = threadIdx.x;
    const int lo = blockIdx.x * SCAN_CHUNK + t * SCAN_VT;
    int local[SCAN_VT];
    int s = 0;
    #pragma unroll
    for (int k = 0; k < SCAN_VT; ++k) {
        int i = lo + k;
        int v = (i < n) ? deg[i] : 0;
        local[k] = v;
        s += v;
    }
    ps[t] = s;
    __syncthreads();
    for (int off = 1; off < SCAN_BS; off <<= 1) {
        int v = (t >= off) ? ps[t - off] : 0;
        __syncthreads();
        ps[t] += v;
        __syncthreads();
    }
    int run = blockoff[blockIdx.x] + ((t > 0) ? ps[t - 1] : 0);
    #pragma unroll
    for (int k = 0; k < SCAN_VT; ++k) {
        int i = lo + k;
        if (i < n) {
            rowstart[i] = run;
            cursor[i]   = run;
            run += local[k];
        }
    }
}

__global__ __launch_bounds__(256)
void k_fill(const int* __restrict__ src, const int* __restrict__ dst,
            const int* __restrict__ typ, int* __restrict__ cursor,
            int* __restrict__ list, int E)
{
    int e = blockIdx.x * 256 + threadIdx.x;
    if (e < E) {
        int pos = atomicAdd(&cursor[dst[e] * NR + typ[e]], 1);
        list[pos] = src[e];
    }
}

// ---------------------------------------------------------------------------
// Gather-aggregate: QUARTER-WAVE (16 lanes) per dst node; lane owns channels
// 8c..8c+7 (ushort8). 6 relation chains concurrent -> each load touches FOUR
// rows. S written with NON-TEMPORAL stores (keeps h hot in L3).
// ---------------------------------------------------------------------------
__global__ __launch_bounds__(256)
void gather_agg(const unsigned short* __restrict__ h,
                const int* __restrict__ rowstart,
                const int* __restrict__ list,
                unsigned short* __restrict__ S)
{
    const int v = (blockIdx.x * 256 + threadIdx.x) >> 4;   // NN*16 == grid*256
    const int lane = threadIdx.x & 15;
    const u16x8* hp = (const u16x8*)h;

    const int b0 = rowstart[v * NR + 0];
    const int b1 = rowstart[v * NR + 1];
    const int b2 = rowstart[v * NR + 2];
    const int b3 = rowstart[v * NR + 3];
    const int b4 = rowstart[v * NR + 4];
    const int b5 = rowstart[v * NR + 5];
    const int b6 = rowstart[v * NR + 6];
    const int n0 = b1 - b0, n1 = b2 - b1, n2 = b3 - b2;
    const int n3 = b4 - b3, n4 = b5 - b4, n5 = b6 - b5;
    const int kmax = max(max(max(n0, n1), max(n2, n3)), max(n4, n5));

    f32x8 a0 = {}, a1 = {}, a2 = {}, a3 = {}, a4 = {}, a5 = {};

    for (int k = 0; k < kmax; ++k) {
        int i0 = (k < n0) ? (b0 + k) : 0;
        int i1 = (k < n1) ? (b1 + k) : 0;
        int i2 = (k < n2) ? (b2 + k) : 0;
        int i3 = (k < n3) ? (b3 + k) : 0;
        int i4 = (k < n4) ? (b4 + k) : 0;
        int i5 = (k < n5) ? (b5 + k) : 0;
        int s0 = list[i0], s1 = list[i1], s2 = list[i2];
        int s3 = list[i3], s4 = list[i4], s5 = list[i5];
        u16x8 u0 = hp[(size_t)s0 * 16 + lane];
        u16x8 u1 = hp[(size_t)s1 * 16 + lane];
        u16x8 u2 = hp[(size_t)s2 * 16 + lane];
        u16x8 u3 = hp[(size_t)s3 * 16 + lane];
        u16x8 u4 = hp[(size_t)s4 * 16 + lane];
        u16x8 u5 = hp[(size_t)s5 * 16 + lane];
        if (k < n0) a0 += cvt8(u0);
        if (k < n1) a1 += cvt8(u1);
        if (k < n2) a2 += cvt8(u2);
        if (k < n3) a3 += cvt8(u3);
        if (k < n4) a4 += cvt8(u4);
        if (k < n5) a5 += cvt8(u5);
    }

    u16x8* o = (u16x8*)(S + (size_t)v * (NR * LOW));
    u16x8 w;
    #pragma unroll
    for (int i = 0; i < 8; ++i) w[i] = f2bf(a0[i]);
    __builtin_nontemporal_store(w, &o[0 * 16 + lane]);
    #pragma unroll
    for (int i = 0; i < 8; ++i) w[i] = f2bf(a1[i]);
    __builtin_nontemporal_store(w, &o[1 * 16 + lane]);
    #pragma unroll
    for (int i = 0; i < 8; ++i) w[i] = f2bf(a2[i]);
    __builtin_nontemporal_store(w, &o[2 * 16 + lane]);
    #pragma unroll
    for (int i = 0; i < 8; ++i) w[i] = f2bf(a3[i]);
    __builtin_nontemporal_store(w, &o[3 * 16 + lane]);
    #pragma unroll
    for (int i = 0; i < 8; ++i) w[i] = f2bf(a4[i]);
    __builtin_nontemporal_store(w, &o[4 * 16 + lane]);
    #pragma unroll
    for (int i = 0; i < 8; ++i) w[i] = f2bf(a5[i]);
    __builtin_nontemporal_store(w, &o[5 * 16 + lane]);
}

extern "C" void kernel_launch(void* const* d_in, const int* in_sizes, int n_in,
                              void* d_out, int out_size, void* d_ws, size_t ws_size,
                              hipStream_t stream)
{
    (void)in_sizes; (void)n_in; (void)out_size; (void)ws_size;

    const float* h_origin = (const float*)d_in[0];
    const int*   esrc     = (const int*)d_in[1];
    const int*   edst     = (const int*)d_in[2];
    const int*   etyp     = (const int*)d_in[3];
    const float* W_lower  = (const float*)d_in[4];
    const float* b_lower  = (const float*)d_in[5];
    const float* Wl[3]    = {(const float*)d_in[6], (const float*)d_in[8], (const float*)d_in[10]};
    const float* bl[3]    = {(const float*)d_in[7], (const float*)d_in[9], (const float*)d_in[11]};
    const float* W_upper  = (const float*)d_in[12];
    const float* b_upper  = (const float*)d_in[13];
    const float* W_skip   = (const float*)d_in[14];
    const float* b_skip   = (const float*)d_in[15];
    float*       out      = (float*)d_out;

    // Workspace layout
    unsigned short* hob = (unsigned short*)d_ws;          // [NN,512] bf16
    unsigned short* h   = hob + (size_t)NN * HID;         // [NN,128]
    unsigned short* S   = h + (size_t)NN * LOW;           // [NN,768]
    unsigned short* wlt = S + (size_t)NN * NR * LOW;      // [128,512]^T
    unsigned short* w1t = wlt + (size_t)LOW * HID;        // [128,768]^T x3
    unsigned short* w2t = w1t + (size_t)LOW * NR * LOW;
    unsigned short* w3t = w2t + (size_t)LOW * NR * LOW;
    unsigned short* wut = w3t + (size_t)LOW * NR * LOW;   // [512,128]^T
    unsigned short* wst = wut + (size_t)HID * LOW;        // [512,512]^T
    int* deg      = (int*)(wst + (size_t)HID * HID);      // [NBINS]
    int* rowstart = deg + NBINS;                          // [NBINS+1]
    int* cursor   = rowstart + NBINS + 1;                 // [NBINS]
    int* list     = cursor + NBINS;                       // [NE]
    int* blocksum = list + NE;                            // [SCAN_NB]
    int* blockoff = blocksum + SCAN_NB;                   // [SCAN_NB]
    unsigned short* wtL[3] = {w1t, w2t, w3t};

    const unsigned eBlocks = (unsigned)((NE + 255) / 256);
    const unsigned mBlocks = (unsigned)((NN + 127) / 128);   // 782

    // ---- conversions ----
    conv_f32_bf16<<<dim3(2048), dim3(256), 0, stream>>>(
        (const float4*)h_origin, (ushort4*)hob, NN * HID / 4);
    transpose_bf16<<<dim3((HID * LOW + 255) / 256), dim3(256), 0, stream>>>(
        W_lower, wlt, HID, LOW);
    for (int L = 0; L < 3; ++L)
        transpose_bf16<<<dim3((NR * LOW * LOW + 255) / 256), dim3(256), 0, stream>>>(
            Wl[L], wtL[L], NR * LOW, LOW);
    transpose_bf16<<<dim3((LOW * HID + 255) / 256), dim3(256), 0, stream>>>(
        W_upper, wut, LOW, HID);
    transpose_bf16<<<dim3((HID * HID + 255) / 256), dim3(256), 0, stream>>>(
        W_skip, wst, HID, HID);

    // ---- CSR build over (dst, rel) bins ----
    hipMemsetAsync(deg, 0, NBINS * sizeof(int), stream);
    k_hist<<<dim3(eBlocks), dim3(256), 0, stream>>>(edst, etyp, deg, NE);
    k_scan_part<<<dim3(SCAN_NB), dim3(SCAN_BS), 0, stream>>>(deg, blocksum, NBINS);
    k_scan_mid<<<dim3(1), dim3(64), 0, stream>>>(blocksum, blockoff, rowstart, SCAN_NB, NBINS);
    k_scan_final<<<dim3(SCAN_NB), dim3(SCAN_BS), 0, stream>>>(deg, blockoff, rowstart, cursor, NBINS);
    k_fill<<<dim3(eBlocks), dim3(256), 0, stream>>>(esrc, edst, etyp, cursor, list, NE);

    // ---- lower: h = relu(hob @ wlt^T + b_lower) ----
    gemm_bf16<<<dim3(1, mBlocks), dim3(256), 0, stream>>>(
        hob, wlt, b_lower, h, NN, LOW, HID);

    // ---- 3 R-GCN layers ----
    const unsigned gBlocks = (unsigned)(((size_t)NN * 16 + 255) / 256);  // 6250
    for (int L = 0; L < 3; ++L) {
        gather_agg<<<dim3(gBlocks), dim3(256), 0, stream>>>(h, rowstart, list, S);
        gemm_bf16<<<dim3(1, mBlocks), dim3(256), 0, stream>>>(
            S, wtL[L], bl[L], h, NN, LOW, NR * LOW);
    }

    // ---- fused output (1-D grid, XCD swizzle, 2-phase dbuf) ----
    gemm_out_fused<<<dim3((HID / 128) * mBlocks), dim3(256), 0, stream>>>(
        h, wut, b_upper, hob, wst, b_skip, out, NN);
}

// Round 13
// 841.074 us; speedup vs baseline: 1.3424x; 1.0070x over previous
//
#include <hip/hip_runtime.h>
#include <hip/hip_bf16.h>

#define NN 100000
#define NE 1600000
#define HID 512
#define LOW 128
#define NR  6
#define NBINS (NN * NR)

typedef short  bf16x8 __attribute__((ext_vector_type(8)));
typedef float  f32x4  __attribute__((ext_vector_type(4)));
typedef float  f32x8  __attribute__((ext_vector_type(8)));
typedef unsigned short u16x8 __attribute__((ext_vector_type(8)));

__device__ __forceinline__ unsigned short f2bf(float x) {
    __hip_bfloat16 h = __float2bfloat16(x);
    return __builtin_bit_cast(unsigned short, h);
}
__device__ __forceinline__ float bf2f(unsigned short u) {
    return __builtin_bit_cast(float, (unsigned int)u << 16);
}
__device__ __forceinline__ f32x8 cvt8(u16x8 u) {
    f32x8 r;
    #pragma unroll
    for (int i = 0; i < 8; ++i) r[i] = bf2f(u[i]);
    return r;
}

// ---------------------------------------------------------------------------
// Stage 128 rows x 128B (64 bf16 cols) into LDS, XOR-swizzled source
// (global_load_lds writes linearly: wave-uniform base + lane*16).
// ---------------------------------------------------------------------------
__device__ __forceinline__ void stage_rows(const unsigned short* __restrict__ G,
                                           int r0, int k0, int Kstride, int Rmax,
                                           char* lds_base, int tid)
{
    #pragma unroll
    for (int is = 0; is < 4; ++is) {
        int L   = is * 4096 + tid * 16;
        int row = L >> 7;
        int c   = ((L >> 4) & 7) ^ (row & 7);
        int gr  = r0 + row;
        gr = (gr < Rmax) ? gr : (Rmax - 1);
        const char* src = (const char*)G + ((size_t)gr * Kstride + k0) * 2 + c * 16;
        __builtin_amdgcn_global_load_lds(
            (const __attribute__((address_space(1))) void*)src,
            (__attribute__((address_space(3))) void*)(lds_base + is * 4096 + (tid & 192) * 16),
            16, 0, 0);
    }
}

__device__ __forceinline__ bf16x8 lds_frag(const char* lds_base, int row, int clog)
{
    return *(const bf16x8*)(lds_base + row * 128 + ((clog ^ (row & 7)) << 4));
}

// ---------------------------------------------------------------------------
// bf16 MFMA GEMM: C(bf16) = relu(A @ Bt^T + bias). 128x128 tile, 4 waves.
// (round-7 geometry, single-buffered: proven fastest variant)
// ---------------------------------------------------------------------------
__global__ __launch_bounds__(256, 2)
void gemm_bf16(const unsigned short* __restrict__ A,
               const unsigned short* __restrict__ Bt,
               const float* __restrict__ bias,
               unsigned short* __restrict__ C,
               int M, int N, int K)
{
    __shared__ __align__(16) char lA[16384];
    __shared__ __align__(16) char lB[16384];

    const int tid  = threadIdx.x;
    const int lane = tid & 63;
    const int wid  = tid >> 6;
    const int wm   = wid >> 1;
    const int wn   = wid & 1;
    const int m0   = blockIdx.y * 128;
    const int n0   = blockIdx.x * 128;

    f32x4 acc[4][4] = {};

    for (int k0 = 0; k0 < K; k0 += 64) {
        stage_rows(A,  m0, k0, K, M, lA, tid);
        stage_rows(Bt, n0, k0, K, N, lB, tid);
        __syncthreads();
        #pragma unroll
        for (int kk = 0; kk < 2; ++kk) {
            const int clog = kk * 4 + (lane >> 4);
            bf16x8 af[4], bfr[4];
            #pragma unroll
            for (int i = 0; i < 4; ++i)
                af[i] = lds_frag(lA, wm * 64 + i * 16 + (lane & 15), clog);
            #pragma unroll
            for (int j = 0; j < 4; ++j)
                bfr[j] = lds_frag(lB, wn * 64 + j * 16 + (lane & 15), clog);
            #pragma unroll
            for (int i = 0; i < 4; ++i)
                #pragma unroll
                for (int j = 0; j < 4; ++j)
                    acc[i][j] = __builtin_amdgcn_mfma_f32_16x16x32_bf16(
                        af[i], bfr[j], acc[i][j], 0, 0, 0);
        }
        __syncthreads();
    }

    const int col_l = lane & 15;
    const int rgrp  = lane >> 4;
    #pragma unroll
    for (int i = 0; i < 4; ++i) {
        #pragma unroll
        for (int j = 0; j < 4; ++j) {
            int col  = n0 + wn * 64 + j * 16 + col_l;
            float bv = bias[col];
            #pragma unroll
            for (int r = 0; r < 4; ++r) {
                int row = m0 + wm * 64 + i * 16 + rgrp * 4 + r;
                if (row < M)
                    C[(size_t)row * N + col] = f2bf(fmaxf(acc[i][j][r] + bv, 0.f));
            }
        }
    }
}

// ---------------------------------------------------------------------------
// Fused output (round-7 geometry, plain stores):
// out(f32) = relu(h @ Wut^T + bu) + relu(hob @ Wst^T + bs)
// 1-D grid (3128 = 8*391), XCD swizzle: 4 n-tiles of each hob slab share XCD.
// ---------------------------------------------------------------------------
__global__ __launch_bounds__(256, 2)
void gemm_out_fused(const unsigned short* __restrict__ h,
                    const unsigned short* __restrict__ Wut,
                    const float* __restrict__ bu,
                    const unsigned short* __restrict__ hob,
                    const unsigned short* __restrict__ Wst,
                    const float* __restrict__ bs,
                    float* __restrict__ out, int M)
{
    __shared__ __align__(16) char lA[16384];
    __shared__ __align__(16) char lB[16384];

    const int tid  = threadIdx.x;
    const int lane = tid & 63;
    const int wid  = tid >> 6;
    const int wm   = wid >> 1;
    const int wn   = wid & 1;

    const int nwg  = gridDim.x;            // 3128 = 8 * 391
    const int cpx  = nwg >> 3;
    const int idx  = (blockIdx.x & 7) * cpx + (blockIdx.x >> 3);
    const int m0   = (idx >> 2) * 128;
    const int n0   = (idx & 3) * 128;

    f32x4 acc1[4][4] = {};
    f32x4 acc2[4][4] = {};

    for (int k0 = 0; k0 < LOW; k0 += 64) {
        stage_rows(h,   m0, k0, LOW, M,   lA, tid);
        stage_rows(Wut, n0, k0, LOW, HID, lB, tid);
        __syncthreads();
        #pragma unroll
        for (int kk = 0; kk < 2; ++kk) {
            const int clog = kk * 4 + (lane >> 4);
            bf16x8 af[4], bfr[4];
            #pragma unroll
            for (int i = 0; i < 4; ++i)
                af[i] = lds_frag(lA, wm * 64 + i * 16 + (lane & 15), clog);
            #pragma unroll
            for (int j = 0; j < 4; ++j)
                bfr[j] = lds_frag(lB, wn * 64 + j * 16 + (lane & 15), clog);
            #pragma unroll
            for (int i = 0; i < 4; ++i)
                #pragma unroll
                for (int j = 0; j < 4; ++j)
                    acc1[i][j] = __builtin_amdgcn_mfma_f32_16x16x32_bf16(
                        af[i], bfr[j], acc1[i][j], 0, 0, 0);
        }
        __syncthreads();
    }
    for (int k0 = 0; k0 < HID; k0 += 64) {
        stage_rows(hob, m0, k0, HID, M,   lA, tid);
        stage_rows(Wst, n0, k0, HID, HID, lB, tid);
        __syncthreads();
        #pragma unroll
        for (int kk = 0; kk < 2; ++kk) {
            const int clog = kk * 4 + (lane >> 4);
            bf16x8 af[4], bfr[4];
            #pragma unroll
            for (int i = 0; i < 4; ++i)
                af[i] = lds_frag(lA, wm * 64 + i * 16 + (lane & 15), clog);
            #pragma unroll
            for (int j = 0; j < 4; ++j)
                bfr[j] = lds_frag(lB, wn * 64 + j * 16 + (lane & 15), clog);
            #pragma unroll
            for (int i = 0; i < 4; ++i)
                #pragma unroll
                for (int j = 0; j < 4; ++j)
                    acc2[i][j] = __builtin_amdgcn_mfma_f32_16x16x32_bf16(
                        af[i], bfr[j], acc2[i][j], 0, 0, 0);
        }
        __syncthreads();
    }

    const int col_l = lane & 15;
    const int rgrp  = lane >> 4;
    #pragma unroll
    for (int i = 0; i < 4; ++i) {
        #pragma unroll
        for (int j = 0; j < 4; ++j) {
            int col   = n0 + wn * 64 + j * 16 + col_l;
            float bv1 = bu[col], bv2 = bs[col];
            #pragma unroll
            for (int r = 0; r < 4; ++r) {
                int row = m0 + wm * 64 + i * 16 + rgrp * 4 + r;
                if (row < M)
                    out[(size_t)row * HID + col] =
                        fmaxf(acc1[i][j][r] + bv1, 0.f) + fmaxf(acc2[i][j][r] + bv2, 0.f);
            }
        }
    }
}

// ---------------------------------------------------------------------------
// Conversions
// ---------------------------------------------------------------------------
__global__ __launch_bounds__(256)
void conv_f32_bf16(const float4* __restrict__ in, ushort4* __restrict__ out, int n4)
{
    for (int i = blockIdx.x * 256 + threadIdx.x; i < n4; i += gridDim.x * 256) {
        float4 v = in[i];
        ushort4 o;
        o.x = f2bf(v.x); o.y = f2bf(v.y); o.z = f2bf(v.z); o.w = f2bf(v.w);
        out[i] = o;
    }
}

__global__ __launch_bounds__(256)
void transpose_bf16(const float* __restrict__ W, unsigned short* __restrict__ Wt,
                    int R, int C)
{
    int idx = blockIdx.x * 256 + threadIdx.x;
    if (idx < R * C) {
        int r = idx / C, c = idx - r * C;
        Wt[(size_t)c * R + r] = f2bf(W[idx]);
    }
}

// ---------------------------------------------------------------------------
// CSR build keyed by bin = dst*NR + rel. Parallel 3-kernel exclusive scan.
// ---------------------------------------------------------------------------
#define SCAN_VT 8
#define SCAN_BS 256
#define SCAN_CHUNK (SCAN_VT * SCAN_BS)
#define SCAN_NB ((NBINS + SCAN_CHUNK - 1) / SCAN_CHUNK)

__global__ __launch_bounds__(256)
void k_hist(const int* __restrict__ dst, const int* __restrict__ typ,
            int* __restrict__ deg, int E)
{
    int e = blockIdx.x * 256 + threadIdx.x;
    if (e < E) atomicAdd(&deg[dst[e] * NR + typ[e]], 1);
}

__global__ __launch_bounds__(SCAN_BS)
void k_scan_part(const int* __restrict__ deg, int* __restrict__ blocksum, int n)
{
    __shared__ int ps[SCAN_BS];
    const int t = threadIdx.x;
    const int lo = blockIdx.x * SCAN_CHUNK + t * SCAN_VT;
    int s = 0;
    #pragma unroll
    for (int k = 0; k < SCAN_VT; ++k) {
        int i = lo + k;
        if (i < n) s += deg[i];
    }
    ps[t] = s;
    __syncthreads();
    for (int off = SCAN_BS / 2; off > 0; off >>= 1) {
        if (t < off) ps[t] += ps[t + off];
        __syncthreads();
    }
    if (t == 0) blocksum[blockIdx.x] = ps[0];
}

__global__ __launch_bounds__(64)
void k_scan_mid(const int* __restrict__ blocksum, int* __restrict__ blockoff,
                int* __restrict__ rowstart, int nb, int n)
{
    if (threadIdx.x == 0) {
        int run = 0;
        for (int i = 0; i < nb; ++i) { blockoff[i] = run; run += blocksum[i]; }
        rowstart[n] = run;
    }
}

__global__ __launch_bounds__(SCAN_BS)
void k_scan_final(const int* __restrict__ deg, const int* __restrict__ blockoff,
                  int* __restrict__ rowstart, int* __restrict__ cursor, int n)
{
    __shared__ int ps[SCAN_BS];
    const int t = threadIdx.x;
    const int lo = blockIdx.x * SCAN_CHUNK + t * SCAN_VT;
    int local[SCAN_VT];
    int s = 0;
    #pragma unroll
    for (int k = 0; k < SCAN_VT; ++k) {
        int i = lo + k;
        int v = (i < n) ? deg[i] : 0;
        local[k] = v;
        s += v;
    }
    ps[t] = s;
    __syncthreads();
    for (int off = 1; off < SCAN_BS; off <<= 1) {
        int v = (t >= off) ? ps[t - off] : 0;
        __syncthreads();
        ps[t] += v;
        __syncthreads();
    }
    int run = blockoff[blockIdx.x] + ((t > 0) ? ps[t - 1] : 0);
    #pragma unroll
    for (int k = 0; k < SCAN_VT; ++k) {
        int i = lo + k;
        if (i < n) {
            rowstart[i] = run;
            cursor[i]   = run;
            run += local[k];
        }
    }
}

__global__ __launch_bounds__(256)
void k_fill(const int* __restrict__ src, const int* __restrict__ dst,
            const int* __restrict__ typ, int* __restrict__ cursor,
            int* __restrict__ list, int E)
{
    int e = blockIdx.x * 256 + threadIdx.x;
    if (e < E) {
        int pos = atomicAdd(&cursor[dst[e] * NR + typ[e]], 1);
        list[pos] = src[e];
    }
}

// ---------------------------------------------------------------------------
// Gather-aggregate: QUARTER-WAVE (16 lanes) per (dst,rel) BIN. Each walks its
// own ~2.7-edge segment 2-deep (inflation ~1.19x vs 2x for per-node chains),
// one f32x8 accumulator -> ~32 VGPR -> near-max occupancy. MLP from wave
// count. S written non-temporally (protect h L3 residency).
// ---------------------------------------------------------------------------
__global__ __launch_bounds__(256)
void gather_agg(const unsigned short* __restrict__ h,
                const int* __restrict__ rowstart,
                const int* __restrict__ list,
                unsigned short* __restrict__ S)
{
    const int bin  = (blockIdx.x * 256 + threadIdx.x) >> 4;  // NBINS*16 == grid*256
    const int lane = threadIdx.x & 15;
    const u16x8* hp = (const u16x8*)h;

    const int b = rowstart[bin];
    const int e = rowstart[bin + 1];

    f32x8 a0 = {}, a1 = {};

    for (int k = b; k < e; k += 2) {
        bool ok1 = (k + 1 < e);
        int  i1  = ok1 ? (k + 1) : k;
        int  s0  = list[k];
        int  s1  = list[i1];
        u16x8 u0 = hp[(size_t)s0 * 16 + lane];
        u16x8 u1 = hp[(size_t)s1 * 16 + lane];
        a0 += cvt8(u0);
        if (ok1) a1 += cvt8(u1);
    }
    a0 += a1;

    u16x8 w;
    #pragma unroll
    for (int i = 0; i < 8; ++i) w[i] = f2bf(a0[i]);
    __builtin_nontemporal_store(w, (u16x8*)(S + (size_t)bin * LOW) + lane);
}

extern "C" void kernel_launch(void* const* d_in, const int* in_sizes, int n_in,
                              void* d_out, int out_size, void* d_ws, size_t ws_size,
                              hipStream_t stream)
{
    (void)in_sizes; (void)n_in; (void)out_size; (void)ws_size;

    const float* h_origin = (const float*)d_in[0];
    const int*   esrc     = (const int*)d_in[1];
    const int*   edst     = (const int*)d_in[2];
    const int*   etyp     = (const int*)d_in[3];
    const float* W_lower  = (const float*)d_in[4];
    const float* b_lower  = (const float*)d_in[5];
    const float* Wl[3]    = {(const float*)d_in[6], (const float*)d_in[8], (const float*)d_in[10]};
    const float* bl[3]    = {(const float*)d_in[7], (const float*)d_in[9], (const float*)d_in[11]};
    const float* W_upper  = (const float*)d_in[12];
    const float* b_upper  = (const float*)d_in[13];
    const float* W_skip   = (const float*)d_in[14];
    const float* b_skip   = (const float*)d_in[15];
    float*       out      = (float*)d_out;

    // Workspace layout
    unsigned short* hob = (unsigned short*)d_ws;          // [NN,512] bf16
    unsigned short* h   = hob + (size_t)NN * HID;         // [NN,128]
    unsigned short* S   = h + (size_t)NN * LOW;           // [NN,768]
    unsigned short* wlt = S + (size_t)NN * NR * LOW;      // [128,512]^T
    unsigned short* w1t = wlt + (size_t)LOW * HID;        // [128,768]^T x3
    unsigned short* w2t = w1t + (size_t)LOW * NR * LOW;
    unsigned short* w3t = w2t + (size_t)LOW * NR * LOW;
    unsigned short* wut = w3t + (size_t)LOW * NR * LOW;   // [512,128]^T
    unsigned short* wst = wut + (size_t)HID * LOW;        // [512,512]^T
    int* deg      = (int*)(wst + (size_t)HID * HID);      // [NBINS]
    int* rowstart = deg + NBINS;                          // [NBINS+1]
    int* cursor   = rowstart + NBINS + 1;                 // [NBINS]
    int* list     = cursor + NBINS;                       // [NE]
    int* blocksum = list + NE;                            // [SCAN_NB]
    int* blockoff = blocksum + SCAN_NB;                   // [SCAN_NB]
    unsigned short* wtL[3] = {w1t, w2t, w3t};

    const unsigned eBlocks = (unsigned)((NE + 255) / 256);
    const unsigned mBlocks = (unsigned)((NN + 127) / 128);   // 782

    // ---- conversions ----
    conv_f32_bf16<<<dim3(2048), dim3(256), 0, stream>>>(
        (const float4*)h_origin, (ushort4*)hob, NN * HID / 4);
    transpose_bf16<<<dim3((HID * LOW + 255) / 256), dim3(256), 0, stream>>>(
        W_lower, wlt, HID, LOW);
    for (int L = 0; L < 3; ++L)
        transpose_bf16<<<dim3((NR * LOW * LOW + 255) / 256), dim3(256), 0, stream>>>(
            Wl[L], wtL[L], NR * LOW, LOW);
    transpose_bf16<<<dim3((LOW * HID + 255) / 256), dim3(256), 0, stream>>>(
        W_upper, wut, LOW, HID);
    transpose_bf16<<<dim3((HID * HID + 255) / 256), dim3(256), 0, stream>>>(
        W_skip, wst, HID, HID);

    // ---- CSR build over (dst, rel) bins ----
    hipMemsetAsync(deg, 0, NBINS * sizeof(int), stream);
    k_hist<<<dim3(eBlocks), dim3(256), 0, stream>>>(edst, etyp, deg, NE);
    k_scan_part<<<dim3(SCAN_NB), dim3(SCAN_BS), 0, stream>>>(deg, blocksum, NBINS);
    k_scan_mid<<<dim3(1), dim3(64), 0, stream>>>(blocksum, blockoff, rowstart, SCAN_NB, NBINS);
    k_scan_final<<<dim3(SCAN_NB), dim3(SCAN_BS), 0, stream>>>(deg, blockoff, rowstart, cursor, NBINS);
    k_fill<<<dim3(eBlocks), dim3(256), 0, stream>>>(esrc, edst, etyp, cursor, list, NE);

    // ---- lower: h = relu(hob @ wlt^T + b_lower) ----
    gemm_bf16<<<dim3(1, mBlocks), dim3(256), 0, stream>>>(
        hob, wlt, b_lower, h, NN, LOW, HID);

    // ---- 3 R-GCN layers (bin-parallel gather: NBINS*16/256 = 37500 blocks) ----
    const unsigned gBlocks = (unsigned)(((size_t)NBINS * 16) / 256);
    for (int L = 0; L < 3; ++L) {
        gather_agg<<<dim3(gBlocks), dim3(256), 0, stream>>>(h, rowstart, list, S);
        gemm_bf16<<<dim3(1, mBlocks), dim3(256), 0, stream>>>(
            S, wtL[L], bl[L], h, NN, LOW, NR * LOW);
    }

    // ---- fused output (1-D grid, XCD swizzle, plain stores) ----
    gemm_out_fused<<<dim3((HID / 128) * mBlocks), dim3(256), 0, stream>>>(
        h, wut, b_upper, hob, wst, b_skip, out, NN);
}

// Round 14
// 809.493 us; speedup vs baseline: 1.3947x; 1.0390x over previous
//
#include <hip/hip_runtime.h>
#include <hip/hip_bf16.h>

#define NN 100000
#define NE 1600000
#define HID 512
#define LOW 128
#define NR  6
#define NBINS (NN * NR)

typedef short  bf16x8 __attribute__((ext_vector_type(8)));
typedef float  f32x4  __attribute__((ext_vector_type(4)));

__device__ __forceinline__ unsigned short f2bf(float x) {
    __hip_bfloat16 h = __float2bfloat16(x);
    return __builtin_bit_cast(unsigned short, h);
}
__device__ __forceinline__ float bf2f(unsigned short u) {
    return __builtin_bit_cast(float, (unsigned int)u << 16);
}

// ---------------------------------------------------------------------------
// Stage 128 rows x 128B (64 bf16 cols) into LDS, XOR-swizzled source
// (global_load_lds writes linearly: wave-uniform base + lane*16).
// ---------------------------------------------------------------------------
__device__ __forceinline__ void stage_tile(const unsigned short* __restrict__ G,
                                           int r0, int k0, int Kstride, int Rmax,
                                           char* lds_base, int tid)
{
    #pragma unroll
    for (int is = 0; is < 4; ++is) {
        int L   = is * 4096 + tid * 16;
        int row = L >> 7;
        int c   = ((L >> 4) & 7) ^ (row & 7);
        int gr  = r0 + row;
        gr = (gr < Rmax) ? gr : (Rmax - 1);
        const char* src = (const char*)G + ((size_t)gr * Kstride + k0) * 2 + c * 16;
        __builtin_amdgcn_global_load_lds(
            (const __attribute__((address_space(1))) void*)src,
            (__attribute__((address_space(3))) void*)(lds_base + is * 4096 + (tid & 192) * 16),
            16, 0, 0);
    }
}

__device__ __forceinline__ bf16x8 lds_frag(const char* lds_base, int row, int clog)
{
    return *(const bf16x8*)(lds_base + row * 128 + ((clog ^ (row & 7)) << 4));
}

// ---------------------------------------------------------------------------
// bf16 MFMA GEMM: C(bf16) = relu(A @ Bt^T + bias). 128x128 tile, 4 waves.
// (round-7 geometry: best measured of all variants tried)
// ---------------------------------------------------------------------------
__global__ __launch_bounds__(256, 2)
void gemm_bf16(const unsigned short* __restrict__ A,
               const unsigned short* __restrict__ Bt,
               const float* __restrict__ bias,
               unsigned short* __restrict__ C,
               int M, int N, int K)
{
    __shared__ __align__(16) char lA[16384];
    __shared__ __align__(16) char lB[16384];

    const int tid  = threadIdx.x;
    const int lane = tid & 63;
    const int wid  = tid >> 6;
    const int wm   = wid >> 1;
    const int wn   = wid & 1;
    const int m0   = blockIdx.y * 128;
    const int n0   = blockIdx.x * 128;

    f32x4 acc[4][4] = {};

    for (int k0 = 0; k0 < K; k0 += 64) {
        stage_tile(A,  m0, k0, K, M, lA, tid);
        stage_tile(Bt, n0, k0, K, N, lB, tid);
        __syncthreads();
        #pragma unroll
        for (int kk = 0; kk < 2; ++kk) {
            const int clog = kk * 4 + (lane >> 4);
            bf16x8 af[4], bfr[4];
            #pragma unroll
            for (int i = 0; i < 4; ++i)
                af[i] = lds_frag(lA, wm * 64 + i * 16 + (lane & 15), clog);
            #pragma unroll
            for (int j = 0; j < 4; ++j)
                bfr[j] = lds_frag(lB, wn * 64 + j * 16 + (lane & 15), clog);
            #pragma unroll
            for (int i = 0; i < 4; ++i)
                #pragma unroll
                for (int j = 0; j < 4; ++j)
                    acc[i][j] = __builtin_amdgcn_mfma_f32_16x16x32_bf16(
                        af[i], bfr[j], acc[i][j], 0, 0, 0);
        }
        __syncthreads();
    }

    const int col_l = lane & 15;
    const int rgrp  = lane >> 4;
    #pragma unroll
    for (int i = 0; i < 4; ++i) {
        #pragma unroll
        for (int j = 0; j < 4; ++j) {
            int col  = n0 + wn * 64 + j * 16 + col_l;
            float bv = bias[col];
            #pragma unroll
            for (int r = 0; r < 4; ++r) {
                int row = m0 + wm * 64 + i * 16 + rgrp * 4 + r;
                if (row < M)
                    C[(size_t)row * N + col] = f2bf(fmaxf(acc[i][j][r] + bv, 0.f));
            }
        }
    }
}

// ---------------------------------------------------------------------------
// Fused output: out(f32) = relu(h @ Wut^T + bu) + relu(hob @ Wst^T + bs)
// 1-D grid (3128 = 8*391), XCD swizzle: the 4 n-tiles of each 128-row hob
// slab run consecutively on the SAME XCD -> A-slab L2 reuse. Plain stores.
// ---------------------------------------------------------------------------
__global__ __launch_bounds__(256, 2)
void gemm_out_fused(const unsigned short* __restrict__ h,
                    const unsigned short* __restrict__ Wut,
                    const float* __restrict__ bu,
                    const unsigned short* __restrict__ hob,
                    const unsigned short* __restrict__ Wst,
                    const float* __restrict__ bs,
                    float* __restrict__ out, int M)
{
    __shared__ __align__(16) char lA[16384];
    __shared__ __align__(16) char lB[16384];

    const int tid  = threadIdx.x;
    const int lane = tid & 63;
    const int wid  = tid >> 6;
    const int wm   = wid >> 1;
    const int wn   = wid & 1;

    const int nwg  = gridDim.x;            // 3128 = 8 * 391
    const int cpx  = nwg >> 3;
    const int idx  = (blockIdx.x & 7) * cpx + (blockIdx.x >> 3);
    const int m0   = (idx >> 2) * 128;
    const int n0   = (idx & 3) * 128;

    f32x4 acc1[4][4] = {};
    f32x4 acc2[4][4] = {};

    for (int k0 = 0; k0 < LOW; k0 += 64) {
        stage_tile(h,   m0, k0, LOW, M,   lA, tid);
        stage_tile(Wut, n0, k0, LOW, HID, lB, tid);
        __syncthreads();
        #pragma unroll
        for (int kk = 0; kk < 2; ++kk) {
            const int clog = kk * 4 + (lane >> 4);
            bf16x8 af[4], bfr[4];
            #pragma unroll
            for (int i = 0; i < 4; ++i)
                af[i] = lds_frag(lA, wm * 64 + i * 16 + (lane & 15), clog);
            #pragma unroll
            for (int j = 0; j < 4; ++j)
                bfr[j] = lds_frag(lB, wn * 64 + j * 16 + (lane & 15), clog);
            #pragma unroll
            for (int i = 0; i < 4; ++i)
                #pragma unroll
                for (int j = 0; j < 4; ++j)
                    acc1[i][j] = __builtin_amdgcn_mfma_f32_16x16x32_bf16(
                        af[i], bfr[j], acc1[i][j], 0, 0, 0);
        }
        __syncthreads();
    }
    for (int k0 = 0; k0 < HID; k0 += 64) {
        stage_tile(hob, m0, k0, HID, M,   lA, tid);
        stage_tile(Wst, n0, k0, HID, HID, lB, tid);
        __syncthreads();
        #pragma unroll
        for (int kk = 0; kk < 2; ++kk) {
            const int clog = kk * 4 + (lane >> 4);
            bf16x8 af[4], bfr[4];
            #pragma unroll
            for (int i = 0; i < 4; ++i)
                af[i] = lds_frag(lA, wm * 64 + i * 16 + (lane & 15), clog);
            #pragma unroll
            for (int j = 0; j < 4; ++j)
                bfr[j] = lds_frag(lB, wn * 64 + j * 16 + (lane & 15), clog);
            #pragma unroll
            for (int i = 0; i < 4; ++i)
                #pragma unroll
                for (int j = 0; j < 4; ++j)
                    acc2[i][j] = __builtin_amdgcn_mfma_f32_16x16x32_bf16(
                        af[i], bfr[j], acc2[i][j], 0, 0, 0);
        }
        __syncthreads();
    }

    const int col_l = lane & 15;
    const int rgrp  = lane >> 4;
    #pragma unroll
    for (int i = 0; i < 4; ++i) {
        #pragma unroll
        for (int j = 0; j < 4; ++j) {
            int col   = n0 + wn * 64 + j * 16 + col_l;
            float bv1 = bu[col], bv2 = bs[col];
            #pragma unroll
            for (int r = 0; r < 4; ++r) {
                int row = m0 + wm * 64 + i * 16 + rgrp * 4 + r;
                if (row < M)
                    out[(size_t)row * HID + col] =
                        fmaxf(acc1[i][j][r] + bv1, 0.f) + fmaxf(acc2[i][j][r] + bv2, 0.f);
            }
        }
    }
}

// ---------------------------------------------------------------------------
// Conversions
// ---------------------------------------------------------------------------
__global__ __launch_bounds__(256)
void conv_f32_bf16(const float4* __restrict__ in, ushort4* __restrict__ out, int n4)
{
    for (int i = blockIdx.x * 256 + threadIdx.x; i < n4; i += gridDim.x * 256) {
        float4 v = in[i];
        ushort4 o;
        o.x = f2bf(v.x); o.y = f2bf(v.y); o.z = f2bf(v.z); o.w = f2bf(v.w);
        out[i] = o;
    }
}

// All 5 weight transposes in ONE launch. Cumulative element offsets:
// wlt 65536 | w1t 98304 | w2t 98304 | w3t 98304 | wut 65536 | wst 262144
// total = 688128 = 2688 * 256 exactly.
__global__ __launch_bounds__(256)
void transpose_all(const float* __restrict__ Wl_, const float* __restrict__ W1,
                   const float* __restrict__ W2, const float* __restrict__ W3,
                   const float* __restrict__ Wu, const float* __restrict__ Ws_,
                   unsigned short* __restrict__ wlt, unsigned short* __restrict__ w1t,
                   unsigned short* __restrict__ w2t, unsigned short* __restrict__ w3t,
                   unsigned short* __restrict__ wut, unsigned short* __restrict__ wst)
{
    int idx = blockIdx.x * 256 + threadIdx.x;
    const float* W;
    unsigned short* T;
    int R, local, cshift;
    if (idx < 65536)       { W = Wl_; T = wlt; R = 512; local = idx;          cshift = 7; }
    else if (idx < 163840) { W = W1;  T = w1t; R = 768; local = idx - 65536;  cshift = 7; }
    else if (idx < 262144) { W = W2;  T = w2t; R = 768; local = idx - 163840; cshift = 7; }
    else if (idx < 360448) { W = W3;  T = w3t; R = 768; local = idx - 262144; cshift = 7; }
    else if (idx < 425984) { W = Wu;  T = wut; R = 128; local = idx - 360448; cshift = 9; }
    else                   { W = Ws_; T = wst; R = 512; local = idx - 425984; cshift = 9; }
    int r = local >> cshift;
    int c = local & ((1 << cshift) - 1);
    T[(size_t)c * R + r] = f2bf(W[local]);
}

// ---------------------------------------------------------------------------
// CSR build keyed by bin = dst*NR + rel. Parallel 3-kernel exclusive scan.
// ---------------------------------------------------------------------------
#define SCAN_VT 8
#define SCAN_BS 256
#define SCAN_CHUNK (SCAN_VT * SCAN_BS)
#define SCAN_NB ((NBINS + SCAN_CHUNK - 1) / SCAN_CHUNK)

__global__ __launch_bounds__(256)
void k_hist(const int* __restrict__ dst, const int* __restrict__ typ,
            int* __restrict__ deg, int E)
{
    int e = blockIdx.x * 256 + threadIdx.x;
    if (e < E) atomicAdd(&deg[dst[e] * NR + typ[e]], 1);
}

__global__ __launch_bounds__(SCAN_BS)
void k_scan_part(const int* __restrict__ deg, int* __restrict__ blocksum, int n)
{
    __shared__ int ps[SCAN_BS];
    const int t = threadIdx.x;
    const int lo = blockIdx.x * SCAN_CHUNK + t * SCAN_VT;
    int s = 0;
    #pragma unroll
    for (int k = 0; k < SCAN_VT; ++k) {
        int i = lo + k;
        if (i < n) s += deg[i];
    }
    ps[t] = s;
    __syncthreads();
    for (int off = SCAN_BS / 2; off > 0; off >>= 1) {
        if (t < off) ps[t] += ps[t + off];
        __syncthreads();
    }
    if (t == 0) blocksum[blockIdx.x] = ps[0];
}

__global__ __launch_bounds__(64)
void k_scan_mid(const int* __restrict__ blocksum, int* __restrict__ blockoff,
                int* __restrict__ rowstart, int nb, int n)
{
    if (threadIdx.x == 0) {
        int run = 0;
        for (int i = 0; i < nb; ++i) { blockoff[i] = run; run += blocksum[i]; }
        rowstart[n] = run;
    }
}

__global__ __launch_bounds__(SCAN_BS)
void k_scan_final(const int* __restrict__ deg, const int* __restrict__ blockoff,
                  int* __restrict__ rowstart, int* __restrict__ cursor, int n)
{
    __shared__ int ps[SCAN_BS];
    const int t = threadIdx.x;
    const int lo = blockIdx.x * SCAN_CHUNK + t * SCAN_VT;
    int local[SCAN_VT];
    int s = 0;
    #pragma unroll
    for (int k = 0; k < SCAN_VT; ++k) {
        int i = lo + k;
        int v = (i < n) ? deg[i] : 0;
        local[k] = v;
        s += v;
    }
    ps[t] = s;
    __syncthreads();
    for (int off = 1; off < SCAN_BS; off <<= 1) {
        int v = (t >= off) ? ps[t - off] : 0;
        __syncthreads();
        ps[t] += v;
        __syncthreads();
    }
    int run = blockoff[blockIdx.x] + ((t > 0) ? ps[t - 1] : 0);
    #pragma unroll
    for (int k = 0; k < SCAN_VT; ++k) {
        int i = lo + k;
        if (i < n) {
            rowstart[i] = run;
            cursor[i]   = run;
            run += local[k];
        }
    }
}

__global__ __launch_bounds__(256)
void k_fill(const int* __restrict__ src, const int* __restrict__ dst,
            const int* __restrict__ typ, int* __restrict__ cursor,
            int* __restrict__ list, int E)
{
    int e = blockIdx.x * 256 + threadIdx.x;
    if (e < E) {
        int pos = atomicAdd(&cursor[dst[e] * NR + typ[e]], 1);
        list[pos] = src[e];
    }
}

// ---------------------------------------------------------------------------
// Gather-aggregate (round-7 form, best measured): HALF-WAVE per dst node;
// lane owns channels 4c..4c+3 (ushort4, 32 lanes x 8B = one 256B row).
// 6 relation chains walked concurrently; plain S stores.
// ---------------------------------------------------------------------------
__global__ __launch_bounds__(256)
void gather_agg(const unsigned short* __restrict__ h,
                const int* __restrict__ rowstart,
                const int* __restrict__ list,
                unsigned short* __restrict__ S)
{
    const int v = (blockIdx.x * 256 + threadIdx.x) >> 5;   // half-wave per node
    if (v >= NN) return;
    const int lane = threadIdx.x & 31;
    const ushort4* hp = (const ushort4*)h;                 // 32 ushort4 per row

    const int b0 = rowstart[v * NR + 0];
    const int b1 = rowstart[v * NR + 1];
    const int b2 = rowstart[v * NR + 2];
    const int b3 = rowstart[v * NR + 3];
    const int b4 = rowstart[v * NR + 4];
    const int b5 = rowstart[v * NR + 5];
    const int b6 = rowstart[v * NR + 6];
    const int n0 = b1 - b0, n1 = b2 - b1, n2 = b3 - b2;
    const int n3 = b4 - b3, n4 = b5 - b4, n5 = b6 - b5;
    const int kmax = max(max(max(n0, n1), max(n2, n3)), max(n4, n5));

    float a0x=0.f,a0y=0.f,a0z=0.f,a0w=0.f, a1x=0.f,a1y=0.f,a1z=0.f,a1w=0.f;
    float a2x=0.f,a2y=0.f,a2z=0.f,a2w=0.f, a3x=0.f,a3y=0.f,a3z=0.f,a3w=0.f;
    float a4x=0.f,a4y=0.f,a4z=0.f,a4w=0.f, a5x=0.f,a5y=0.f,a5z=0.f,a5w=0.f;

    for (int k = 0; k < kmax; ++k) {
        int i0 = (k < n0) ? (b0 + k) : 0;
        int i1 = (k < n1) ? (b1 + k) : 0;
        int i2 = (k < n2) ? (b2 + k) : 0;
        int i3 = (k < n3) ? (b3 + k) : 0;
        int i4 = (k < n4) ? (b4 + k) : 0;
        int i5 = (k < n5) ? (b5 + k) : 0;
        int s0 = list[i0], s1 = list[i1], s2 = list[i2];
        int s3 = list[i3], s4 = list[i4], s5 = list[i5];
        ushort4 u0 = hp[(size_t)s0 * 32 + lane];
        ushort4 u1 = hp[(size_t)s1 * 32 + lane];
        ushort4 u2 = hp[(size_t)s2 * 32 + lane];
        ushort4 u3 = hp[(size_t)s3 * 32 + lane];
        ushort4 u4 = hp[(size_t)s4 * 32 + lane];
        ushort4 u5 = hp[(size_t)s5 * 32 + lane];
        if (k < n0) { a0x += bf2f(u0.x); a0y += bf2f(u0.y); a0z += bf2f(u0.z); a0w += bf2f(u0.w); }
        if (k < n1) { a1x += bf2f(u1.x); a1y += bf2f(u1.y); a1z += bf2f(u1.z); a1w += bf2f(u1.w); }
        if (k < n2) { a2x += bf2f(u2.x); a2y += bf2f(u2.y); a2z += bf2f(u2.z); a2w += bf2f(u2.w); }
        if (k < n3) { a3x += bf2f(u3.x); a3y += bf2f(u3.y); a3z += bf2f(u3.z); a3w += bf2f(u3.w); }
        if (k < n4) { a4x += bf2f(u4.x); a4y += bf2f(u4.y); a4z += bf2f(u4.z); a4w += bf2f(u4.w); }
        if (k < n5) { a5x += bf2f(u5.x); a5y += bf2f(u5.y); a5z += bf2f(u5.z); a5w += bf2f(u5.w); }
    }

    ushort4* o = (ushort4*)(S + (size_t)v * (NR * LOW));
    ushort4 w;
    w.x=f2bf(a0x); w.y=f2bf(a0y); w.z=f2bf(a0z); w.w=f2bf(a0w); o[0*32+lane]=w;
    w.x=f2bf(a1x); w.y=f2bf(a1y); w.z=f2bf(a1z); w.w=f2bf(a1w); o[1*32+lane]=w;
    w.x=f2bf(a2x); w.y=f2bf(a2y); w.z=f2bf(a2z); w.w=f2bf(a2w); o[2*32+lane]=w;
    w.x=f2bf(a3x); w.y=f2bf(a3y); w.z=f2bf(a3z); w.w=f2bf(a3w); o[3*32+lane]=w;
    w.x=f2bf(a4x); w.y=f2bf(a4y); w.z=f2bf(a4z); w.w=f2bf(a4w); o[4*32+lane]=w;
    w.x=f2bf(a5x); w.y=f2bf(a5y); w.z=f2bf(a5z); w.w=f2bf(a5w); o[5*32+lane]=w;
}

extern "C" void kernel_launch(void* const* d_in, const int* in_sizes, int n_in,
                              void* d_out, int out_size, void* d_ws, size_t ws_size,
                              hipStream_t stream)
{
    (void)in_sizes; (void)n_in; (void)out_size; (void)ws_size;

    const float* h_origin = (const float*)d_in[0];
    const int*   esrc     = (const int*)d_in[1];
    const int*   edst     = (const int*)d_in[2];
    const int*   etyp     = (const int*)d_in[3];
    const float* W_lower  = (const float*)d_in[4];
    const float* b_lower  = (const float*)d_in[5];
    const float* Wl[3]    = {(const float*)d_in[6], (const float*)d_in[8], (const float*)d_in[10]};
    const float* bl[3]    = {(const float*)d_in[7], (const float*)d_in[9], (const float*)d_in[11]};
    const float* W_upper  = (const float*)d_in[12];
    const float* b_upper  = (const float*)d_in[13];
    const float* W_skip   = (const float*)d_in[14];
    const float* b_skip   = (const float*)d_in[15];
    float*       out      = (float*)d_out;

    // Workspace layout
    unsigned short* hob = (unsigned short*)d_ws;          // [NN,512] bf16
    unsigned short* h   = hob + (size_t)NN * HID;         // [NN,128]
    unsigned short* S   = h + (size_t)NN * LOW;           // [NN,768]
    unsigned short* wlt = S + (size_t)NN * NR * LOW;      // [128,512]^T
    unsigned short* w1t = wlt + (size_t)LOW * HID;        // [128,768]^T x3
    unsigned short* w2t = w1t + (size_t)LOW * NR * LOW;
    unsigned short* w3t = w2t + (size_t)LOW * NR * LOW;
    unsigned short* wut = w3t + (size_t)LOW * NR * LOW;   // [512,128]^T
    unsigned short* wst = wut + (size_t)HID * LOW;        // [512,512]^T
    int* deg      = (int*)(wst + (size_t)HID * HID);      // [NBINS]
    int* rowstart = deg + NBINS;                          // [NBINS+1]
    int* cursor   = rowstart + NBINS + 1;                 // [NBINS]
    int* list     = cursor + NBINS;                       // [NE]
    int* blocksum = list + NE;                            // [SCAN_NB]
    int* blockoff = blocksum + SCAN_NB;                   // [SCAN_NB]
    unsigned short* wtL[3] = {w1t, w2t, w3t};

    const unsigned eBlocks = (unsigned)((NE + 255) / 256);
    const unsigned mBlocks = (unsigned)((NN + 127) / 128);   // 782

    // ---- conversions (2 launches) ----
    conv_f32_bf16<<<dim3(2048), dim3(256), 0, stream>>>(
        (const float4*)h_origin, (ushort4*)hob, NN * HID / 4);
    transpose_all<<<dim3(2688), dim3(256), 0, stream>>>(
        W_lower, Wl[0], Wl[1], Wl[2], W_upper, W_skip,
        wlt, w1t, w2t, w3t, wut, wst);

    // ---- CSR build over (dst, rel) bins ----
    hipMemsetAsync(deg, 0, NBINS * sizeof(int), stream);
    k_hist<<<dim3(eBlocks), dim3(256), 0, stream>>>(edst, etyp, deg, NE);
    k_scan_part<<<dim3(SCAN_NB), dim3(SCAN_BS), 0, stream>>>(deg, blocksum, NBINS);
    k_scan_mid<<<dim3(1), dim3(64), 0, stream>>>(blocksum, blockoff, rowstart, SCAN_NB, NBINS);
    k_scan_final<<<dim3(SCAN_NB), dim3(SCAN_BS), 0, stream>>>(deg, blockoff, rowstart, cursor, NBINS);
    k_fill<<<dim3(eBlocks), dim3(256), 0, stream>>>(esrc, edst, etyp, cursor, list, NE);

    // ---- lower: h = relu(hob @ wlt^T + b_lower) ----
    gemm_bf16<<<dim3(1, mBlocks), dim3(256), 0, stream>>>(
        hob, wlt, b_lower, h, NN, LOW, HID);

    // ---- 3 R-GCN layers ----
    const unsigned gBlocks = (unsigned)(((size_t)NN * 32 + 255) / 256);  // 12500
    for (int L = 0; L < 3; ++L) {
        gather_agg<<<dim3(gBlocks), dim3(256), 0, stream>>>(h, rowstart, list, S);
        gemm_bf16<<<dim3(1, mBlocks), dim3(256), 0, stream>>>(
            S, wtL[L], bl[L], h, NN, LOW, NR * LOW);
    }

    // ---- fused output (1-D grid, XCD swizzle, plain stores) ----
    gemm_out_fused<<<dim3((HID / 128) * mBlocks), dim3(256), 0, stream>>>(
        h, wut, b_upper, hob, wst, b_skip, out, NN);
}